// Round 8
// baseline (336.850 us; speedup 1.0000x reference)
//
#include <hip/hip_runtime.h>
#include <math.h>

constexpr int L = 256;
constexpr float EPS = 1e-6f;

typedef float f32x4 __attribute__((ext_vector_type(4)));

__device__ inline float wave_sum(float v) {
#pragma unroll
    for (int off = 32; off > 0; off >>= 1) v += __shfl_down(v, off, 64);
    return v;
}
__device__ inline int wave_min(int v) {
#pragma unroll
    for (int off = 32; off > 0; off >>= 1) v = min(v, __shfl_down(v, off, 64));
    return v;
}
__device__ inline int wave_max(int v) {
#pragma unroll
    for (int off = 32; off > 0; off >>= 1) v = max(v, __shfl_down(v, off, 64));
    return v;
}

// Fused per-sample kernel: one 256-thread block streams its whole sample
// (64 float4/thread, 4+4 register double-buffer, nontemporal), then computes
// box + generated-mask sum + ratio inline. No cross-block state.
__global__ __launch_bounds__(256) void sample_kernel(
    const float* __restrict__ Yp, const float* __restrict__ Yg,
    float* __restrict__ ratios) {
    const int b = blockIdx.x;
    const int t = threadIdx.x;
    const float* yp = Yp + (size_t)b * L * L;
    const f32x4* yp4 = (const f32x4*)yp;
    const f32x4* yg4 = (const f32x4*)(Yg + (size_t)b * L * L);

    // Prologue: load iteration 0's 4+4 float4.
    f32x4 Pc[4], Gc[4], Pn[4], Gn[4];
#pragma unroll
    for (int k = 0; k < 4; ++k) {
        Pc[k] = __builtin_nontemporal_load(yp4 + (k << 8) + t);
        Gc[k] = __builtin_nontemporal_load(yg4 + (k << 8) + t);
    }

    // Geometry (data-independent): float4 idx j = it*1024 + k*256 + t
    //   row(it,k) = (t>>6) + 4*(it*4+k) ; cols c0..c0+3, c0=(t&63)*4
    const int w = t >> 6;
    const int c0 = (t & 63) << 2;

    float sum_p = 0.f, sum_pg = 0.f;
    int anyg_t = 0;
    unsigned long long rowbits = 0ull;            // bit n=it*4+k -> row w+4n
    unsigned cb0 = 0, cb1 = 0, cb2 = 0, cb3 = 0;  // per-column presence
#pragma unroll
    for (int it = 0; it < 16; ++it) {
        if (it < 15) {  // issue next iteration's loads before consuming current
#pragma unroll
            for (int k = 0; k < 4; ++k) {
                const int off = ((it + 1) << 10) + (k << 8) + t;
                Pn[k] = __builtin_nontemporal_load(yp4 + off);
                Gn[k] = __builtin_nontemporal_load(yg4 + off);
            }
        }
#pragma unroll
        for (int k = 0; k < 4; ++k) {
            const f32x4 p = Pc[k], g = Gc[k];
            sum_p  += (p[0] + p[1]) + (p[2] + p[3]);
            sum_pg += p[0] * g[0] + p[1] * g[1] + p[2] * g[2] + p[3] * g[3];
            anyg_t |= (g[0] > 0.f) | (g[1] > 0.f) | (g[2] > 0.f) | (g[3] > 0.f);
            const unsigned bx = p[0] > 0.5f, by = p[1] > 0.5f,
                           bz = p[2] > 0.5f, bw = p[3] > 0.5f;
            rowbits |= (unsigned long long)(bx | by | bz | bw) << (it * 4 + k);
            cb0 |= bx; cb1 |= by; cb2 |= bz; cb3 |= bw;
        }
#pragma unroll
        for (int k = 0; k < 4; ++k) { Pc[k] = Pn[k]; Gc[k] = Gn[k]; }
    }

    // Collapse to per-thread box candidates.
    int minr = 0x7FFFFFFF, maxr = -1, minc = 0x7FFFFFFF, maxc = -1;
    if (rowbits) {
        minr = w + 4 * __builtin_ctzll(rowbits);
        maxr = w + 4 * (63 - __builtin_clzll(rowbits));
        const unsigned colbits = cb0 | (cb1 << 1) | (cb2 << 2) | (cb3 << 3);
        minc = c0 + __builtin_ctz(colbits);
        maxc = c0 + (31 - __builtin_clz(colbits));
    }

    // Wave reduce, then LDS across the 4 waves.
    const int wave = t >> 6, lane = t & 63;
    const float wsp = wave_sum(sum_p);
    const float wspg = wave_sum(sum_pg);
    const int wanyg = __any(anyg_t);
    const int wminr = wave_min(minr), wmaxr = wave_max(maxr);
    const int wminc = wave_min(minc), wmaxc = wave_max(maxc);

    __shared__ float sh_p[4], sh_pg[4];
    __shared__ int sh_a[4], sh_minr[4], sh_maxr[4], sh_minc[4], sh_maxc[4];
    if (lane == 0) {
        sh_p[wave] = wsp; sh_pg[wave] = wspg; sh_a[wave] = wanyg;
        sh_minr[wave] = wminr; sh_maxr[wave] = wmaxr;
        sh_minc[wave] = wminc; sh_maxc[wave] = wmaxc;
    }
    __syncthreads();

    // Merge block-level stats redundantly on all threads.
    float sp = 0.f, spg = 0.f;
    int anyg = 0, mnr = 0x7FFFFFFF, mxr = -1, mnc = 0x7FFFFFFF, mxc = -1;
#pragma unroll
    for (int i = 0; i < 4; ++i) {
        sp += sh_p[i]; spg += sh_pg[i]; anyg |= sh_a[i];
        mnr = min(mnr, sh_minr[i]); mxr = max(mxr, sh_maxr[i]);
        mnc = min(mnc, sh_minc[i]); mxc = max(mxc, sh_maxc[i]);
    }

    // Faithful to reference (incl. the row/col swap and Python floor division).
    const bool any_r = mxr >= 0, any_c = mxc >= 0;
    const int left  = any_r ? mnr : 0;
    const int right = any_r ? (L - 1 - mxr) : 0;
    const int up    = any_c ? mnc : 0;
    const int down  = any_c ? (L - 1 - mxc) : 0;
    const int x_r = (right - left) >> 1;   // arithmetic shift = floor div
    const int y_r = (down - up) >> 1;
    const float gt0 = (float)(left + x_r); // compared against COLUMN coord
    const float gt1 = (float)(up + y_r);   // compared against ROW coord

    // Generated-mask branch: tiny bounded loop over the mask box (all threads,
    // block-uniform condition). Mask empty if x_r==0 or y_r==0 (inf/nan -> h
    // not > 0.1 in the reference).
    const bool gen = (!anyg) && (x_r != 0) && (y_r != 0);
    float pos = 0.f;
    if (gen) {
        const float inv_xr = 1.f / (float)x_r;
        const float inv_yr = 1.f / (float)y_r;
        // mask needs d0^4+d1^4 < ln(10)*4/9 => |d| <= 1.0059 ; pad a bit
        const float mx = fabsf((float)x_r) * 1.02f + 1.f;
        const float my = fabsf((float)y_r) * 1.02f + 1.f;
        const int cl = max(0, (int)floorf(gt0 - mx));
        const int ch = min(L - 1, (int)ceilf(gt0 + mx));
        const int rl = max(0, (int)floorf(gt1 - my));
        const int rh = min(L - 1, (int)ceilf(gt1 + my));
        const int W = ch - cl + 1, H = rh - rl + 1;
        for (int idx = t; idx < W * H; idx += 256) {
            const int r = rl + idx / W;
            const int c = cl + idx % W;
            float d0 = ((float)c - gt0) * inv_xr;
            float d1 = ((float)r - gt1) * inv_yr;
            d0 *= d0; d0 *= d0;    // d0^4
            d1 *= d1; d1 *= d1;    // d1^4
            const float h = __expf(-2.25f * (d0 + d1));  // exp(-h'/(2/3)^2)
            if (h > 0.1f) pos += yp[r * L + c];
        }
    }
    __syncthreads();  // everyone has read sh_* ; safe to reuse sh_p
    const float wpos = wave_sum(pos);
    if (lane == 0) sh_p[wave] = wpos;
    __syncthreads();
    if (t == 0) {
        const float posg = sh_p[0] + sh_p[1] + sh_p[2] + sh_p[3];
        const float positive = anyg ? spg : (gen ? posg : 0.f);
        ratios[b] = (sp - positive) / (positive + EPS);
    }
}

__global__ __launch_bounds__(256) void finalize_kernel(
    const float* __restrict__ ratios, float* __restrict__ out, int B) {
    float v = 0.f;
    for (int i = threadIdx.x; i < B; i += 256) v += ratios[i];
    v = wave_sum(v);
    __shared__ float part[4];
    const int wave = threadIdx.x >> 6, lane = threadIdx.x & 63;
    if (lane == 0) part[wave] = v;
    __syncthreads();
    if (threadIdx.x == 0) {
        const float total = part[0] + part[1] + part[2] + part[3];
        out[0] = (total == 0.f) ? 0.f : logf(total) / (float)B;
    }
}

extern "C" void kernel_launch(void* const* d_in, const int* in_sizes, int n_in,
                              void* d_out, int out_size, void* d_ws, size_t ws_size,
                              hipStream_t stream) {
    const float* Yp = (const float*)d_in[0];
    const float* Yg = (const float*)d_in[1];
    const int B = in_sizes[0] / (L * L);
    float* ratios = (float*)d_ws;   // B floats of scratch
    sample_kernel<<<B, 256, 0, stream>>>(Yp, Yg, ratios);
    finalize_kernel<<<1, 256, 0, stream>>>(ratios, (float*)d_out, B);
}

// Round 9
// 255.640 us; speedup vs baseline: 1.3177x; 1.3177x over previous
//
#include <hip/hip_runtime.h>
#include <math.h>

constexpr int L = 256;
constexpr float EPS = 1e-6f;

typedef float f32x4 __attribute__((ext_vector_type(4)));

__device__ inline float wave_sum(float v) {
#pragma unroll
    for (int off = 32; off > 0; off >>= 1) v += __shfl_down(v, off, 64);
    return v;
}
__device__ inline int wave_min(int v) {
#pragma unroll
    for (int off = 32; off > 0; off >>= 1) v = min(v, __shfl_down(v, off, 64));
    return v;
}
__device__ inline int wave_max(int v) {
#pragma unroll
    for (int off = 32; off > 0; off >>= 1) v = max(v, __shfl_down(v, off, 64));
    return v;
}

// Fused per-sample kernel: one 256-thread block streams its whole sample as
// TWO sequential 128-row halves, each with the R7-proven 8-iteration 4+4
// register double-buffer (bounded VGPR), then computes box + generated-mask
// sum + ratio inline. No cross-block state.
__global__ __launch_bounds__(256) void sample_kernel(
    const float* __restrict__ Yp, const float* __restrict__ Yg,
    float* __restrict__ ratios) {
    const int b = blockIdx.x;
    const int t = threadIdx.x;
    const float* yp = Yp + (size_t)b * L * L;

    // Geometry (data-independent): within half h, float4 idx j = it*1024+k*256+t
    //   row(h,it,k) = h*128 + (t>>6) + 16*it + 4*k ; cols c0..c0+3, c0=(t&63)*4
    const int w = t >> 6;
    const int c0 = (t & 63) << 2;

    float sum_p = 0.f, sum_pg = 0.f;
    int anyg_t = 0;
    int minr = 0x7FFFFFFF, maxr = -1;
    unsigned cb0 = 0, cb1 = 0, cb2 = 0, cb3 = 0;  // per-column presence

#pragma unroll 1   // keep halves sequential: bounds register pressure (R8: 256 VGPR, spills)
    for (int h = 0; h < 2; ++h) {
        const f32x4* yp4 = (const f32x4*)yp + h * 8192;
        const f32x4* yg4 = (const f32x4*)(Yg + (size_t)b * L * L) + h * 8192;

        // Prologue: load iteration 0's 4+4 float4.
        f32x4 Pc[4], Gc[4], Pn[4], Gn[4];
#pragma unroll
        for (int k = 0; k < 4; ++k) {
            Pc[k] = __builtin_nontemporal_load(yp4 + (k << 8) + t);
            Gc[k] = __builtin_nontemporal_load(yg4 + (k << 8) + t);
        }

        unsigned rowbits = 0u;   // bit n=it*4+k -> row h*128 + w + 4n
#pragma unroll
        for (int it = 0; it < 8; ++it) {
            if (it < 7) {  // next iteration's loads in flight while consuming
#pragma unroll
                for (int k = 0; k < 4; ++k) {
                    const int off = ((it + 1) << 10) + (k << 8) + t;
                    Pn[k] = __builtin_nontemporal_load(yp4 + off);
                    Gn[k] = __builtin_nontemporal_load(yg4 + off);
                }
            }
#pragma unroll
            for (int k = 0; k < 4; ++k) {
                const f32x4 p = Pc[k], g = Gc[k];
                sum_p  += (p[0] + p[1]) + (p[2] + p[3]);
                sum_pg += p[0] * g[0] + p[1] * g[1] + p[2] * g[2] + p[3] * g[3];
                anyg_t |= (g[0] > 0.f) | (g[1] > 0.f) | (g[2] > 0.f) | (g[3] > 0.f);
                const unsigned bx = p[0] > 0.5f, by = p[1] > 0.5f,
                               bz = p[2] > 0.5f, bw = p[3] > 0.5f;
                rowbits |= (bx | by | bz | bw) << (it * 4 + k);
                cb0 |= bx; cb1 |= by; cb2 |= bz; cb3 |= bw;
            }
#pragma unroll
            for (int k = 0; k < 4; ++k) { Pc[k] = Pn[k]; Gc[k] = Gn[k]; }
        }
        if (rowbits) {
            minr = min(minr, h * 128 + w + 4 * __builtin_ctz(rowbits));
            maxr = max(maxr, h * 128 + w + 4 * (31 - __builtin_clz(rowbits)));
        }
    }

    // Column candidates from accumulated per-column presence.
    int minc = 0x7FFFFFFF, maxc = -1;
    const unsigned colbits = cb0 | (cb1 << 1) | (cb2 << 2) | (cb3 << 3);
    if (colbits) {
        minc = c0 + __builtin_ctz(colbits);
        maxc = c0 + (31 - __builtin_clz(colbits));
    }

    // Wave reduce, then LDS across the 4 waves.
    const int wave = t >> 6, lane = t & 63;
    const float wsp = wave_sum(sum_p);
    const float wspg = wave_sum(sum_pg);
    const int wanyg = __any(anyg_t);
    const int wminr = wave_min(minr), wmaxr = wave_max(maxr);
    const int wminc = wave_min(minc), wmaxc = wave_max(maxc);

    __shared__ float sh_p[4], sh_pg[4];
    __shared__ int sh_a[4], sh_minr[4], sh_maxr[4], sh_minc[4], sh_maxc[4];
    if (lane == 0) {
        sh_p[wave] = wsp; sh_pg[wave] = wspg; sh_a[wave] = wanyg;
        sh_minr[wave] = wminr; sh_maxr[wave] = wmaxr;
        sh_minc[wave] = wminc; sh_maxc[wave] = wmaxc;
    }
    __syncthreads();

    // Merge block-level stats redundantly on all threads.
    float sp = 0.f, spg = 0.f;
    int anyg = 0, mnr = 0x7FFFFFFF, mxr = -1, mnc = 0x7FFFFFFF, mxc = -1;
#pragma unroll
    for (int i = 0; i < 4; ++i) {
        sp += sh_p[i]; spg += sh_pg[i]; anyg |= sh_a[i];
        mnr = min(mnr, sh_minr[i]); mxr = max(mxr, sh_maxr[i]);
        mnc = min(mnc, sh_minc[i]); mxc = max(mxc, sh_maxc[i]);
    }

    // Faithful to reference (incl. the row/col swap and Python floor division).
    const bool any_r = mxr >= 0, any_c = mxc >= 0;
    const int left  = any_r ? mnr : 0;
    const int right = any_r ? (L - 1 - mxr) : 0;
    const int up    = any_c ? mnc : 0;
    const int down  = any_c ? (L - 1 - mxc) : 0;
    const int x_r = (right - left) >> 1;   // arithmetic shift = floor div
    const int y_r = (down - up) >> 1;
    const float gt0 = (float)(left + x_r); // compared against COLUMN coord
    const float gt1 = (float)(up + y_r);   // compared against ROW coord

    // Generated-mask branch: tiny bounded loop over the mask box (all threads,
    // block-uniform condition). Mask empty if x_r==0 or y_r==0 (inf/nan -> h
    // not > 0.1 in the reference).
    const bool gen = (!anyg) && (x_r != 0) && (y_r != 0);
    float pos = 0.f;
    if (gen) {
        const float inv_xr = 1.f / (float)x_r;
        const float inv_yr = 1.f / (float)y_r;
        // mask needs d0^4+d1^4 < ln(10)*4/9 => |d| <= 1.0059 ; pad a bit
        const float mx = fabsf((float)x_r) * 1.02f + 1.f;
        const float my = fabsf((float)y_r) * 1.02f + 1.f;
        const int cl = max(0, (int)floorf(gt0 - mx));
        const int ch = min(L - 1, (int)ceilf(gt0 + mx));
        const int rl = max(0, (int)floorf(gt1 - my));
        const int rh = min(L - 1, (int)ceilf(gt1 + my));
        const int W = ch - cl + 1, H = rh - rl + 1;
        for (int idx = t; idx < W * H; idx += 256) {
            const int r = rl + idx / W;
            const int c = cl + idx % W;
            float d0 = ((float)c - gt0) * inv_xr;
            float d1 = ((float)r - gt1) * inv_yr;
            d0 *= d0; d0 *= d0;    // d0^4
            d1 *= d1; d1 *= d1;    // d1^4
            const float h = __expf(-2.25f * (d0 + d1));  // exp(-h'/(2/3)^2)
            if (h > 0.1f) pos += yp[r * L + c];
        }
    }
    __syncthreads();  // everyone has read sh_* ; safe to reuse sh_p
    const float wpos = wave_sum(pos);
    if (lane == 0) sh_p[wave] = wpos;
    __syncthreads();
    if (t == 0) {
        const float posg = sh_p[0] + sh_p[1] + sh_p[2] + sh_p[3];
        const float positive = anyg ? spg : (gen ? posg : 0.f);
        ratios[b] = (sp - positive) / (positive + EPS);
    }
}

__global__ __launch_bounds__(256) void finalize_kernel(
    const float* __restrict__ ratios, float* __restrict__ out, int B) {
    float v = 0.f;
    for (int i = threadIdx.x; i < B; i += 256) v += ratios[i];
    v = wave_sum(v);
    __shared__ float part[4];
    const int wave = threadIdx.x >> 6, lane = threadIdx.x & 63;
    if (lane == 0) part[wave] = v;
    __syncthreads();
    if (threadIdx.x == 0) {
        const float total = part[0] + part[1] + part[2] + part[3];
        out[0] = (total == 0.f) ? 0.f : logf(total) / (float)B;
    }
}

extern "C" void kernel_launch(void* const* d_in, const int* in_sizes, int n_in,
                              void* d_out, int out_size, void* d_ws, size_t ws_size,
                              hipStream_t stream) {
    const float* Yp = (const float*)d_in[0];
    const float* Yg = (const float*)d_in[1];
    const int B = in_sizes[0] / (L * L);
    float* ratios = (float*)d_ws;   // B floats of scratch
    sample_kernel<<<B, 256, 0, stream>>>(Yp, Yg, ratios);
    finalize_kernel<<<1, 256, 0, stream>>>(ratios, (float*)d_out, B);
}